// Round 9
// baseline (366.027 us; speedup 1.0000x reference)
//
#include <hip/hip_runtime.h>
#include <hip/hip_bf16.h>

typedef __attribute__((ext_vector_type(8))) short short8;
typedef __attribute__((ext_vector_type(4))) float float4v;
typedef __attribute__((ext_vector_type(2))) float float2v;
typedef __attribute__((ext_vector_type(4))) unsigned uint4v;

#define S_A 0.04419417382415922f   // 1/(16*sqrt(2)) : a2, and a1*s2
#define S_B 0.025515518153991442f  // 1/(16*sqrt(6)) : a2/sqrt(3), and a1/sqrt(6)
#define S_C 0.0625f                // 1/16 : a1

// Pack two fp32 -> two bf16 (RNE) in one dword: low = a, high = b.
// Native v_cvt_pk_bf16_f32 (no builtin on gfx950). R4: halved VALUBusy.
static __device__ __forceinline__ unsigned pkbf(float a, float b) {
    unsigned r;
    asm("v_cvt_pk_bf16_f32 %0, %1, %2" : "=v"(r) : "v"(a), "v"(b));
    return r;
}

// ---- Prep: W (5 x 16^3 fp32) -> bf16 in MFMA B-fragment layout in d_ws ----
// path ids after reorder: 0=w0, 1=w2, 2=w1, 3=w3, 4=w4
// addr: k=c*32+kk, lane=(kk>>3)*16+w, j=kk&7 -> wout[((c*5+p)*64+lane)*8+j]
__global__ void wprep_kernel(const float* __restrict__ wA, const float* __restrict__ wB,
                             const float* __restrict__ wC, const float* __restrict__ wD,
                             const float* __restrict__ wE, unsigned short* __restrict__ wout)
{
    int e = blockIdx.x * 256 + threadIdx.x;
    if (e >= 5 * 4096) return;
    int p = e >> 12;
    int rem = e & 4095;                    // rem = k*16 + w
    const float* wp = (p == 0) ? wA : (p == 1) ? wB : (p == 2) ? wC : (p == 3) ? wD : wE;
    unsigned u = __builtin_bit_cast(unsigned, wp[rem]);
    u += 0x7fffu + ((u >> 16) & 1u);       // RNE to bf16
    int k = rem >> 4, w = rem & 15;
    int c = k >> 5, kk = k & 31;
    int lane = ((kk >> 3) << 4) | w;
    int j = kk & 7;
    wout[(((c * 5 + p) * 64 + lane) << 3) | j] = (unsigned short)(u >> 16);
}

// 3 balanced wave-groups per 16-row z-tile (block = 192 threads = 3 waves).
//   G0 "A": m0 (w0), m1 (w2), m10, m12 (w4 diag)
//   G1 "B": m2,m3,m4 (w1), m5 = p12-p21 (w3), m9 = p12+p21 (w4)
//   G2 "C": m6 = p20-p02, m7 = p01-p10 (w3); m8 = p01+p10, m11 = p02+p20 (w4)
// A-frag: lane l holds A[row=l&15][k=c*32+(l>>4)*8+j]; B-frag: W[k][w=l&15]
// C/D: lane l, reg r -> D[row=(l>>4)*4+r][col=l&15]
template<int G>
static __device__ __forceinline__ int pathof(int i) {
    if constexpr (G == 0) return (i == 0) ? 0 : (i == 1) ? 1 : 4;   // w0, w2, w4
    if constexpr (G == 1) return (i == 0) ? 2 : (i == 1) ? 3 : 4;   // w1, w3, w4
    return (i == 0) ? 3 : 4;                                        // w3, w4
}

template<int G>
static __device__ __forceinline__ void run_group(
    const float* __restrict__ xr, int l, const short8* __restrict__ wbase,
    float* __restrict__ out, long long z0)
{
    const int r  = l & 15;
    const int g  = l >> 4;
    const int v0 = (g & 1) * 8;
    const int uo = g >> 1;

    // v-side cache (float2 over cell pairs 2t, 2t+1)
    float2v Xv[4], Yv[4], Zv[4];
    float2v A0v[4];
    {
        float b[24];
        #pragma unroll
        for (int q = 0; q < 6; q++)
            *(float4v*)&b[q * 4] = *(const float4v*)(xr + 16 + v0 * 3 + q * 4);
        #pragma unroll
        for (int t = 0; t < 4; t++) {
            Xv[t] = (float2v){b[6 * t + 0], b[6 * t + 3]};
            Yv[t] = (float2v){b[6 * t + 1], b[6 * t + 4]};
            Zv[t] = (float2v){b[6 * t + 2], b[6 * t + 5]};
        }
        if constexpr (G == 0) {
            float a[8];
            #pragma unroll
            for (int q = 0; q < 2; q++)
                *(float4v*)&a[q * 4] = *(const float4v*)(xr + v0 + q * 4);
            #pragma unroll
            for (int t = 0; t < 4; t++) A0v[t] = (float2v){a[2 * t], a[2 * t + 1]};
        }
    }

    constexpr int NS = (G == 1) ? 5 : 4;   // accumulators / m-channels
    constexpr int NP = (G == 2) ? 2 : 3;   // weight paths used

    float4v acc[NS];
    #pragma unroll
    for (int s = 0; s < NS; s++) acc[s] = (float4v){0.f, 0.f, 0.f, 0.f};

    #pragma unroll
    for (int c = 0; c < 8; c++) {
        short8 wf[NP];
        #pragma unroll
        for (int i = 0; i < NP; i++) wf[i] = wbase[(c * 5 + pathof<G>(i)) * 64 + l];

        const int u = c * 2 + uo;
        float u0 = 0.f, ux = 0.f, uy, uz;
        if constexpr (G != 2) u0 = xr[u];
        if constexpr (G != 1) ux = xr[16 + u * 3 + 0];
        uy = xr[16 + u * 3 + 1];
        uz = xr[16 + u * 3 + 2];

        unsigned fri[NS][4];
        #pragma unroll
        for (int t = 0; t < 4; t++) {
            const float2v X = Xv[t], Y = Yv[t], Z = Zv[t];
            if constexpr (G == 0) {
                float2v b0  = u0 * A0v[t];
                float2v p00 = ux * X, p11 = uy * Y, p22 = uz * Z;
                float2v t01 = p00 + p11;
                float2v b1  = t01 + p22;
                float2v b10 = 2.0f * p22 - t01;
                float2v b12 = p00 - p11;
                fri[0][t] = pkbf(b0.x, b0.y);
                fri[1][t] = pkbf(b1.x, b1.y);
                fri[2][t] = pkbf(b10.x, b10.y);
                fri[3][t] = pkbf(b12.x, b12.y);
            }
            if constexpr (G == 1) {
                float2v b2 = u0 * X, b3 = u0 * Y, b4 = u0 * Z;
                float2v p12 = uy * Z;
                float2v b5 = p12 - uz * Y;     // m5 = p12 - p21
                float2v b9 = p12 + uz * Y;     // m9 = p12 + p21
                fri[0][t] = pkbf(b2.x, b2.y);
                fri[1][t] = pkbf(b3.x, b3.y);
                fri[2][t] = pkbf(b4.x, b4.y);
                fri[3][t] = pkbf(b5.x, b5.y);
                fri[4][t] = pkbf(b9.x, b9.y);
            }
            if constexpr (G == 2) {
                float2v p01 = ux * Y;
                float2v b7  = p01 - uy * X;    // m7 = p01 - p10
                float2v b8  = p01 + uy * X;    // m8 = p01 + p10
                float2v p02 = ux * Z;
                float2v b6  = uz * X - p02;    // m6 = p20 - p02
                float2v b11 = p02 + uz * X;    // m11 = p02 + p20
                fri[0][t] = pkbf(b6.x, b6.y);
                fri[1][t] = pkbf(b7.x, b7.y);
                fri[2][t] = pkbf(b8.x, b8.y);
                fri[3][t] = pkbf(b11.x, b11.y);
            }
        }

        #pragma unroll
        for (int s = 0; s < NS; s++) {
            short8 frm = __builtin_bit_cast(short8, *(uint4v*)fri[s]);
            // B-fragment selection per channel:
            //  G0: s0->w0, s1->w2, s2,s3->w4
            //  G1: s0-2->w1, s3->w3, s4->w4
            //  G2: s0,s1->w3, s2,s3->w4
            int wi;
            if constexpr (G == 0) wi = (s == 0) ? 0 : (s == 1) ? 1 : 2;
            if constexpr (G == 1) wi = (s <= 2) ? 0 : (s == 3) ? 1 : 2;
            if constexpr (G == 2) wi = (s <= 1) ? 0 : 1;
            acc[s] = __builtin_amdgcn_mfma_f32_16x16x32_bf16(frm, wf[wi], acc[s], 0, 0, 0);
        }
    }

    // ---- Epilogue: scale + store. w = l&15, rows z0 + g*4 + reg ----
    const int w = r;
    float* outp = out + (z0 + g * 4) * 192;
    #pragma unroll
    for (int reg = 0; reg < 4; reg++) {
        float* rowp = outp + reg * 192;
        if constexpr (G == 0) {
            rowp[w]               = S_A * acc[0][reg] + S_B * acc[1][reg];  // m0
            rowp[112 + w * 5 + 2] = S_B * acc[2][reg];                      // m10
            rowp[112 + w * 5 + 4] = S_A * acc[3][reg];                      // m12
        }
        if constexpr (G == 1) {
            rowp[16 + w * 3 + 0]  = S_C * acc[0][reg];                      // m2
            rowp[16 + w * 3 + 1]  = S_C * acc[1][reg];                      // m3
            rowp[16 + w * 3 + 2]  = S_C * acc[2][reg];                      // m4
            rowp[64 + w * 3 + 0]  = S_A * acc[3][reg];                      // m5
            rowp[112 + w * 5 + 1] = S_A * acc[4][reg];                      // m9
        }
        if constexpr (G == 2) {
            rowp[64 + w * 3 + 1]  = S_A * acc[0][reg];                      // m6
            rowp[64 + w * 3 + 2]  = S_A * acc[1][reg];                      // m7
            rowp[112 + w * 5 + 0] = S_A * acc[2][reg];                      // m8
            rowp[112 + w * 5 + 3] = S_A * acc[3][reg];                      // m11
        }
    }
}

// R9: grid-stride (long-lived blocks, no dispatch churn — R7 showed this can
// reach 56% occupancy) + VGPR capped at 64 via min-waves=8 (R8's natural
// allocation ballooned to 116 from the W-hoist and occupancy collapsed to
// 12.8%). Cap 64 >= R4's natural 60, so no spill expected; the cap also
// denies the compiler room to hoist W, keeping the verified R4 loop shape.
__global__ __launch_bounds__(192, 8)
void tsq_kernel(const float* __restrict__ x,
                const unsigned short* __restrict__ wfrag,
                float* __restrict__ out,
                int nrows)
{
    // one 16-row z-tile per iteration; stride 68 keeps LDS aliasing 2-way free
    __shared__ __attribute__((aligned(16))) float xlds[16 * 68];

    const int tid = threadIdx.x;
    const int wave = tid >> 6;
    const int l = tid & 63;
    const short8* wbase = (const short8*)wfrag;
    const int ntiles = (nrows + 15) / 16;

    for (int tile = blockIdx.x; tile < ntiles; tile += gridDim.x) {
        const long long z0 = (long long)tile * 16;

        // stage 16 rows x 64 floats (= 256 float4) over 192 threads, coalesced
        {
            const float* xg = x + z0 * 64;
            {
                int f = tid * 4;
                int row = f >> 6, col = f & 63;
                float4v v = {0.f, 0.f, 0.f, 0.f};
                if (z0 + row < nrows) v = *(const float4v*)(xg + f);
                *(float4v*)&xlds[row * 68 + col] = v;
            }
            if (tid < 64) {
                int f = 768 + tid * 4;
                int row = f >> 6, col = f & 63;
                float4v v = {0.f, 0.f, 0.f, 0.f};
                if (z0 + row < nrows) v = *(const float4v*)(xg + f);
                *(float4v*)&xlds[row * 68 + col] = v;
            }
        }
        __syncthreads();

        const float* xr = &xlds[(l & 15) * 68];
        if      (wave == 0) run_group<0>(xr, l, wbase, out, z0);
        else if (wave == 1) run_group<1>(xr, l, wbase, out, z0);
        else                run_group<2>(xr, l, wbase, out, z0);

        __syncthreads();   // xlds is overwritten by the next iteration
    }
}

extern "C" void kernel_launch(void* const* d_in, const int* in_sizes, int n_in,
                              void* d_out, int out_size, void* d_ws, size_t ws_size,
                              hipStream_t stream) {
    const float* x  = (const float*)d_in[0];
    const float* w0 = (const float*)d_in[1];
    const float* w1 = (const float*)d_in[2];
    const float* w2 = (const float*)d_in[3];
    const float* w3 = (const float*)d_in[4];
    const float* w4 = (const float*)d_in[5];
    float* out = (float*)d_out;
    unsigned short* wfrag = (unsigned short*)d_ws;   // 40 KB used
    (void)ws_size; (void)n_in; (void)out_size;

    const int nrows = in_sizes[0] / 64;              // 100000
    const int ntiles = (nrows + 15) / 16;            // 6250
    const int nblocks = (ntiles < 2048) ? ntiles : 2048;

    // path order: {w0, w2, w1, w3, w4}
    wprep_kernel<<<dim3(80), dim3(256), 0, stream>>>(w0, w2, w1, w3, w4, wfrag);
    tsq_kernel<<<dim3(nblocks), dim3(192), 0, stream>>>(x, wfrag, out, nrows);
}

// Round 10
// 122.253 us; speedup vs baseline: 2.9940x; 2.9940x over previous
//
#include <hip/hip_runtime.h>
#include <hip/hip_bf16.h>

typedef __attribute__((ext_vector_type(8))) short short8;
typedef __attribute__((ext_vector_type(4))) float float4v;
typedef __attribute__((ext_vector_type(2))) float float2v;
typedef __attribute__((ext_vector_type(4))) unsigned uint4v;

#define S_A 0.04419417382415922f   // 1/(16*sqrt(2)) : a2, and a1*s2
#define S_B 0.025515518153991442f  // 1/(16*sqrt(6)) : a2/sqrt(3), and a1/sqrt(6)
#define S_C 0.0625f                // 1/16 : a1
#define R_BA 0.5773502691896258f   // S_B/S_A = 1/sqrt(3) (residual for m10)

// Pack two fp32 -> two bf16 (RNE) in one dword: low = a, high = b.
// Native v_cvt_pk_bf16_f32 (no builtin on gfx950). R4: halved VALUBusy.
static __device__ __forceinline__ unsigned pkbf(float a, float b) {
    unsigned r;
    asm("v_cvt_pk_bf16_f32 %0, %1, %2" : "=v"(r) : "v"(a), "v"(b));
    return r;
}

// ---- Prep: W -> bf16, PRE-SCALED, in group-contiguous MFMA B-frag layout ----
// 64 fragments of 1KB each (64 lanes x 8 bf16):
//   frags [ 0,24): G0, c=f/3, i=f%3, paths {w0*S_A, w2*S_B, w4*S_A}
//   frags [24,48): G1, c=(f-24)/3, i%3, paths {w1*S_C, w3*S_A, w4*S_A}
//   frags [48,64): G2, c=(f-48)/2, i%2, paths {w3*S_A, w4*S_A}
// Within a frag: lane, j -> source k = c*32 + (lane>>4)*8 + j, wcol = lane&15,
// element wp[k*16 + wcol] (W stored [u][v][wout], k = u*16+v).
// Group-contiguous => per-c base step is NP*1024B and per-i offsets are
// compile-time immediates (<4KB) => no per-load 64-bit address math in tsq.
__global__ void wprep_kernel(const float* __restrict__ w0, const float* __restrict__ w1,
                             const float* __restrict__ w2, const float* __restrict__ w3,
                             const float* __restrict__ w4, unsigned short* __restrict__ wout)
{
    int e = blockIdx.x * 256 + threadIdx.x;      // 64 frags * 512 shorts = 32768
    if (e >= 64 * 512) return;
    int f = e >> 9;
    int r = e & 511;
    int lane = r >> 3, j = r & 7;

    const float* wp;
    float scl;
    int c;
    if (f < 24)      { c = f / 3;        int i = f % 3;
                       wp  = (i == 0) ? w0 : (i == 1) ? w2 : w4;
                       scl = (i == 1) ? S_B : S_A; }
    else if (f < 48) { int fp = f - 24;  c = fp / 3; int i = fp % 3;
                       wp  = (i == 0) ? w1 : (i == 1) ? w3 : w4;
                       scl = (i == 0) ? S_C : S_A; }
    else             { int fp = f - 48;  c = fp / 2; int i = fp % 2;
                       wp  = (i == 0) ? w3 : w4;
                       scl = S_A; }

    int k = c * 32 + ((lane >> 4) << 3) + j;
    int wcol = lane & 15;
    unsigned u = __builtin_bit_cast(unsigned, scl * wp[k * 16 + wcol]);
    u += 0x7fffu + ((u >> 16) & 1u);             // RNE to bf16
    wout[(f * 64 + lane) * 8 + j] = (unsigned short)(u >> 16);
}

// 3 balanced wave-groups per 16-row z-tile (block = 192 threads = 3 waves).
//   G0 "A": m0 (w0+w2), m10, m12 (w4 diag)
//   G1 "B": m2,m3,m4 (w1), m5 = p12-p21 (w3), m9 = p12+p21 (w4)
//   G2 "C": m6 = p20-p02, m7 = p01-p10 (w3); m8 = p01+p10, m11 = p02+p20 (w4)
// A-frag: lane l holds A[row=l&15][k=c*32+(l>>4)*8+j]; B-frag: W[k][w=l&15]
// C/D: lane l, reg r -> D[row=(l>>4)*4+r][col=l&15]
template<int G>
static __device__ __forceinline__ void run_group(
    const float* __restrict__ xr, int l, const short8* __restrict__ wbase,
    float* __restrict__ out, long long z0)
{
    const int g  = l >> 4;
    const int v0 = (g & 1) * 8;
    const int uo = g >> 1;

    // v-side cache (float2 over cell pairs 2t, 2t+1)
    float2v Xv[4], Yv[4], Zv[4];
    float2v A0v[4];
    {
        float b[24];
        #pragma unroll
        for (int q = 0; q < 6; q++)
            *(float4v*)&b[q * 4] = *(const float4v*)(xr + 16 + v0 * 3 + q * 4);
        #pragma unroll
        for (int t = 0; t < 4; t++) {
            Xv[t] = (float2v){b[6 * t + 0], b[6 * t + 3]};
            Yv[t] = (float2v){b[6 * t + 1], b[6 * t + 4]};
            Zv[t] = (float2v){b[6 * t + 2], b[6 * t + 5]};
        }
        if constexpr (G == 0) {
            float a[8];
            #pragma unroll
            for (int q = 0; q < 2; q++)
                *(float4v*)&a[q * 4] = *(const float4v*)(xr + v0 + q * 4);
            #pragma unroll
            for (int t = 0; t < 4; t++) A0v[t] = (float2v){a[2 * t], a[2 * t + 1]};
        }
    }

    constexpr int NS = (G == 1) ? 5 : 4;   // accumulators / m-channels
    constexpr int NP = (G == 2) ? 2 : 3;   // weight paths used
    constexpr int GBASE = (G == 0) ? 0 : (G == 1) ? 24 : 48;  // frag base

    float4v acc[NS];
    #pragma unroll
    for (int s = 0; s < NS; s++) acc[s] = (float4v){0.f, 0.f, 0.f, 0.f};

    #pragma unroll
    for (int c = 0; c < 8; c++) {
        // group-contiguous: one base step per c, immediate offsets per i
        short8 wf[NP];
        #pragma unroll
        for (int i = 0; i < NP; i++) wf[i] = wbase[(GBASE + c * NP + i) * 64 + l];

        const int u = c * 2 + uo;
        float u0 = 0.f, ux = 0.f, uy, uz;
        if constexpr (G != 2) u0 = xr[u];
        if constexpr (G != 1) ux = xr[16 + u * 3 + 0];
        uy = xr[16 + u * 3 + 1];
        uz = xr[16 + u * 3 + 2];

        unsigned fri[NS][4];
        #pragma unroll
        for (int t = 0; t < 4; t++) {
            const float2v X = Xv[t], Y = Yv[t], Z = Zv[t];
            if constexpr (G == 0) {
                float2v b0  = u0 * A0v[t];
                float2v p00 = ux * X, p11 = uy * Y, p22 = uz * Z;
                float2v t01 = p00 + p11;
                float2v b1  = t01 + p22;
                float2v b10 = 2.0f * p22 - t01;
                float2v b12 = p00 - p11;
                fri[0][t] = pkbf(b0.x, b0.y);
                fri[1][t] = pkbf(b1.x, b1.y);
                fri[2][t] = pkbf(b10.x, b10.y);
                fri[3][t] = pkbf(b12.x, b12.y);
            }
            if constexpr (G == 1) {
                float2v b2 = u0 * X, b3 = u0 * Y, b4 = u0 * Z;
                float2v p12 = uy * Z;
                float2v b5 = p12 - uz * Y;     // m5 = p12 - p21
                float2v b9 = p12 + uz * Y;     // m9 = p12 + p21
                fri[0][t] = pkbf(b2.x, b2.y);
                fri[1][t] = pkbf(b3.x, b3.y);
                fri[2][t] = pkbf(b4.x, b4.y);
                fri[3][t] = pkbf(b5.x, b5.y);
                fri[4][t] = pkbf(b9.x, b9.y);
            }
            if constexpr (G == 2) {
                float2v p01 = ux * Y;
                float2v b7  = p01 - uy * X;    // m7 = p01 - p10
                float2v b8  = p01 + uy * X;    // m8 = p01 + p10
                float2v p02 = ux * Z;
                float2v b6  = uz * X - p02;    // m6 = p20 - p02
                float2v b11 = p02 + uz * X;    // m11 = p02 + p20
                fri[0][t] = pkbf(b6.x, b6.y);
                fri[1][t] = pkbf(b7.x, b7.y);
                fri[2][t] = pkbf(b8.x, b8.y);
                fri[3][t] = pkbf(b11.x, b11.y);
            }
        }

        #pragma unroll
        for (int s = 0; s < NS; s++) {
            short8 frm = __builtin_bit_cast(short8, *(uint4v*)fri[s]);
            // B-fragment selection per channel:
            //  G0: s0->w0, s1->w2, s2,s3->w4
            //  G1: s0-2->w1, s3->w3, s4->w4
            //  G2: s0,s1->w3, s2,s3->w4
            int wi;
            if constexpr (G == 0) wi = (s == 0) ? 0 : (s == 1) ? 1 : 2;
            if constexpr (G == 1) wi = (s <= 2) ? 0 : (s == 3) ? 1 : 2;
            if constexpr (G == 2) wi = (s <= 1) ? 0 : 1;
            acc[s] = __builtin_amdgcn_mfma_f32_16x16x32_bf16(frm, wf[wi], acc[s], 0, 0, 0);
        }
    }

    // ---- Epilogue: store (scales pre-folded into W; m10 residual 1/sqrt3) ----
    const int w = l & 15;
    float* outp = out + (z0 + g * 4) * 192;
    #pragma unroll
    for (int reg = 0; reg < 4; reg++) {
        float* rowp = outp + reg * 192;
        if constexpr (G == 0) {
            rowp[w]               = acc[0][reg] + acc[1][reg];   // m0
            rowp[112 + w * 5 + 2] = R_BA * acc[2][reg];          // m10
            rowp[112 + w * 5 + 4] = acc[3][reg];                 // m12
        }
        if constexpr (G == 1) {
            rowp[16 + w * 3 + 0]  = acc[0][reg];                 // m2
            rowp[16 + w * 3 + 1]  = acc[1][reg];                 // m3
            rowp[16 + w * 3 + 2]  = acc[2][reg];                 // m4
            rowp[64 + w * 3 + 0]  = acc[3][reg];                 // m5
            rowp[112 + w * 5 + 1] = acc[4][reg];                 // m9
        }
        if constexpr (G == 2) {
            rowp[64 + w * 3 + 1]  = acc[0][reg];                 // m6
            rowp[64 + w * 3 + 2]  = acc[1][reg];                 // m7
            rowp[112 + w * 5 + 0] = acc[2][reg];                 // m8
            rowp[112 + w * 5 + 3] = acc[3][reg];                 // m11
        }
    }
}

// R10: R4 structure restored verbatim (proven best: 48.3 us, VGPR 60,
// 6250 independent blocks — beats grid-stride in every measured comparison).
// launch_bounds(192,4) == R4's: natural ~60 VGPR, no spill (R7/R9: min-waves
// >=6 forces VGPR<=40 -> catastrophic scratch spill).
__global__ __launch_bounds__(192, 4)
void tsq_kernel(const float* __restrict__ x,
                const unsigned short* __restrict__ wfrag,
                float* __restrict__ out,
                int nrows)
{
    // one 16-row z-tile per block; stride 68 keeps LDS aliasing at free 2-way
    __shared__ __attribute__((aligned(16))) float xlds[16 * 68];

    const int tid = threadIdx.x;
    const long long z0 = (long long)blockIdx.x * 16;

    // stage 16 rows x 64 floats (= 256 float4) over 192 threads, coalesced
    {
        const float* xg = x + z0 * 64;
        {
            int f = tid * 4;
            int row = f >> 6, col = f & 63;
            float4v v = {0.f, 0.f, 0.f, 0.f};
            if (z0 + row < nrows) v = *(const float4v*)(xg + f);
            *(float4v*)&xlds[row * 68 + col] = v;
        }
        if (tid < 64) {
            int f = 768 + tid * 4;
            int row = f >> 6, col = f & 63;
            float4v v = {0.f, 0.f, 0.f, 0.f};
            if (z0 + row < nrows) v = *(const float4v*)(xg + f);
            *(float4v*)&xlds[row * 68 + col] = v;
        }
    }
    __syncthreads();
    if (z0 >= nrows) return;

    const int wave = tid >> 6;
    const int l = tid & 63;
    const float* xr = &xlds[(l & 15) * 68];
    const short8* wbase = (const short8*)wfrag;

    if      (wave == 0) run_group<0>(xr, l, wbase, out, z0);
    else if (wave == 1) run_group<1>(xr, l, wbase, out, z0);
    else                run_group<2>(xr, l, wbase, out, z0);
}

extern "C" void kernel_launch(void* const* d_in, const int* in_sizes, int n_in,
                              void* d_out, int out_size, void* d_ws, size_t ws_size,
                              hipStream_t stream) {
    const float* x  = (const float*)d_in[0];
    const float* w0 = (const float*)d_in[1];
    const float* w1 = (const float*)d_in[2];
    const float* w2 = (const float*)d_in[3];
    const float* w3 = (const float*)d_in[4];
    const float* w4 = (const float*)d_in[5];
    float* out = (float*)d_out;
    unsigned short* wfrag = (unsigned short*)d_ws;   // 64 KB used (group-contig)
    (void)ws_size; (void)n_in; (void)out_size;

    const int nrows = in_sizes[0] / 64;              // 100000
    const int nblocks = (nrows + 15) / 16;           // 6250

    wprep_kernel<<<dim3(128), dim3(256), 0, stream>>>(w0, w1, w2, w3, w4, wfrag);
    tsq_kernel<<<dim3(nblocks), dim3(192), 0, stream>>>(x, wfrag, out, nrows);
}